// Round 9
// baseline (153.045 us; speedup 1.0000x reference)
//
#include <hip/hip_runtime.h>
#include <hip/hip_bf16.h>
#include <math.h>

#define N_B 2
#define C_CH 256
#define HW_SZ 4096
#define CL_CH 16

typedef __bf16 bf16x8 __attribute__((ext_vector_type(8)));
typedef float f32x4 __attribute__((ext_vector_type(4)));
typedef float f32x16 __attribute__((ext_vector_type(16)));

__device__ __forceinline__ unsigned short f2bf(float x){
  __hip_bfloat16 b = __float2bfloat16(x);   // RTNE
  return *reinterpret_cast<unsigned short*>(&b);
}
// packed f32x2 -> bf16x2 (single v_cvt_pk_bf16_f32)
__device__ __forceinline__ unsigned int cvtpk(float a, float b){
  unsigned int r;
  asm("v_cvt_pk_bf16_f32 %0, %1, %2" : "=v"(r) : "v"(a), "v"(b));
  return r;
}
// tanh = 1 - 2*rcp(1+e^{2x}); NaN-safe at +-inf; rcp err ~1e-7 (<< bf16 ulp)
__device__ __forceinline__ float tanh_fast(float x){
  float e = __expf(2.0f * x);
  return fmaf(-2.0f, __builtin_amdgcn_rcpf(1.0f + e), 1.0f);
}
// async global->LDS, 16B per lane; dst must be wave-uniform base (+lane*16 implicit)
__device__ __forceinline__ void gload16(const void* gsrc, void* lds_dst){
  __builtin_amdgcn_global_load_lds(
      (const __attribute__((address_space(1))) unsigned int*)gsrc,
      (__attribute__((address_space(3))) unsigned int*)lds_dst, 16, 0, 0);
}

// ---------- Stage-1 conv (C->1)
__global__ void k_conv1(const float* __restrict__ f1, const float* __restrict__ f2,
                        const float* __restrict__ w1, const float* __restrict__ w2,
                        const float* __restrict__ b1, const float* __restrict__ b2,
                        float* __restrict__ cv){
  const int i = blockIdx.z, n = blockIdx.y, t = threadIdx.x;
  const int ql = t & 63, cg = t >> 6;
  const int q = blockIdx.x * 64 + ql;
  const float* f = (i ? f2 : f1) + n * C_CH * HW_SZ;
  const float* w = i ? w2 : w1;
  __shared__ float ws[C_CH];
  __shared__ float red[4][72];
  ws[t] = w[t];
  __syncthreads();
  float acc = 0.f;
  #pragma unroll 8
  for (int c = cg * 64; c < cg * 64 + 64; ++c)
    acc += f[c * HW_SZ + q] * ws[c];
  red[cg][ql] = acc;
  __syncthreads();
  if (t < 64){
    float s = red[0][t] + red[1][t] + red[2][t] + red[3][t] + (i ? b2[0] : b1[0]);
    cv[(i * 2 + n) * HW_SZ + blockIdx.x * 64 + t] = s;
  }
}

// ---------- softmax over 4096 per row; grid(4) block 256
__global__ void k_softmax(const float* __restrict__ cv, float* __restrict__ pr){
  const int r = blockIdx.x, t = threadIdx.x;
  const float* x = cv + r * HW_SZ;
  float* y = pr + r * HW_SZ;
  __shared__ float red[256];
  float v[16];
  float m = -1e30f;
  #pragma unroll
  for (int j = 0; j < 16; j++){ v[j] = x[j * 256 + t]; m = fmaxf(m, v[j]); }
  red[t] = m; __syncthreads();
  for (int s = 128; s > 0; s >>= 1){ if (t < s) red[t] = fmaxf(red[t], red[t + s]); __syncthreads(); }
  m = red[0]; __syncthreads();
  float sum = 0.f;
  #pragma unroll
  for (int j = 0; j < 16; j++){ v[j] = __expf(v[j] - m); sum += v[j]; }
  red[t] = sum; __syncthreads();
  for (int s = 128; s > 0; s >>= 1){ if (t < s) red[t] += red[t + s]; __syncthreads(); }
  const float inv = 1.0f / red[0];
  #pragma unroll
  for (int j = 0; j < 16; j++) y[j * 256 + t] = v[j] * inv;
}

// ---------- fs_i = bf16(pr_i * f_i) ; clT_i[q][0..15] = bf16(pw_i @ (pr*f) + pb_i),
// clT rows 32 wide, k in [16,32) zeroed (branch-free MFMA fragments in k_hat)
__global__ void k_scale_cl(const float* __restrict__ f1, const float* __restrict__ f2,
                           const float* __restrict__ pr,
                           const float* __restrict__ pw1, const float* __restrict__ pw2,
                           const float* __restrict__ pb1, const float* __restrict__ pb2,
                           unsigned short* __restrict__ fs1, unsigned short* __restrict__ fs2,
                           unsigned short* __restrict__ clT1, unsigned short* __restrict__ clT2){
  const int i = blockIdx.z, n = blockIdx.y, t = threadIdx.x;
  const int ql = t & 63, cg = t >> 6;
  const int q = blockIdx.x * 64 + ql;
  const float* f = (i ? f2 : f1) + n * C_CH * HW_SZ;
  unsigned short* fs = (i ? fs2 : fs1) + n * C_CH * HW_SZ;
  unsigned short* clT = (i ? clT2 : clT1) + n * 32 * HW_SZ;
  const float* pw = i ? pw2 : pw1;
  const float* pb = i ? pb2 : pb1;
  __shared__ float wls[CL_CH * C_CH];
  __shared__ float red[4][CL_CH][66];
  #pragma unroll
  for (int j = 0; j < 16; j++) wls[j * 256 + t] = pw[j * 256 + t];
  __syncthreads();
  const float p = pr[(i * 2 + n) * HW_SZ + q];
  float acc[16];
  #pragma unroll
  for (int k = 0; k < 16; k++) acc[k] = 0.f;
  for (int c = cg * 64; c < cg * 64 + 64; ++c){
    float vv = f[c * HW_SZ + q] * p;
    fs[c * HW_SZ + q] = f2bf(vv);
    #pragma unroll
    for (int k = 0; k < 16; k++) acc[k] += wls[k * 256 + c] * vv;
  }
  #pragma unroll
  for (int k = 0; k < 16; k++) red[cg][k][ql] = acc[k];
  __syncthreads();
  #pragma unroll
  for (int j = 0; j < 4; j++){
    int e = j * 256 + t; int k = e >> 6, qq = e & 63;
    float s = red[0][k][qq] + red[1][k][qq] + red[2][k][qq] + red[3][k][qq] + pb[k];
    clT[(blockIdx.x * 64 + qq) * 32 + k] = f2bf(s);
  }
  // zero the k in [16,32) pad
  if (t < 128){
    uint4 zv = {0u, 0u, 0u, 0u};
    int qq = t >> 1, half = t & 1;
    *reinterpret_cast<uint4*>(&clT[(blockIdx.x * 64 + qq) * 32 + 16 + half * 8]) = zv;
  }
}

// ---------- fused hat GEMM via MFMA. Tile C=128 x Q=256, split-K over p-quarters.
// out[c,q] = sum_p fs[c,p] * tanh(sum_k v[k,p]*u[k,q])
// grid 512 (XCD-swizzled), block 512 (8 waves), LDS 72KB -> 2 blk/CU.
// Wave mmain tile 64c x 64q (2x2 mfma32 frags -> 1.0 LDS-read per mfma).
__global__ __launch_bounds__(512, 4) void k_hat(
    const unsigned short* __restrict__ fs1, const unsigned short* __restrict__ fs2,
    const unsigned short* __restrict__ clT1, const unsigned short* __restrict__ clT2,
    float* __restrict__ hat1, float* __restrict__ hat2,
    float* __restrict__ pt1, float* __restrict__ pt2,
    float* __restrict__ q2, float* __restrict__ q3){
  const int t = threadIdx.x;
  const int bid = blockIdx.x;
  const int xcd = bid & 7, slot = bid >> 3;  // slot 0..63
  const int z = xcd >> 1;                    // 0..3 -> (n,i); 2 XCDs per (n,i)
  const int n = z & 1, i = z >> 1;
  const int x = slot * 2 + (xcd & 1);        // 0..127
  const int ph = x & 3;                      // p-quarter
  const int cs = (x >> 2) & 1;               // c-half
  const int qt = x >> 3;                     // 0..15
  const int q0 = qt * 256;
  const int c0 = cs * 128;
  const int pbase = ph * 1024;               // 16 chunks of 64

  const unsigned short* fs = (i ? fs2 : fs1) + n * C_CH * HW_SZ;
  const unsigned short* uT = (i ? clT1 : clT2) + n * 32 * HW_SZ;  // q-side [HW][32]
  const unsigned short* vT = (i ? clT2 : clT1) + n * 32 * HW_SZ;  // p-side [HW][32]
  float* out;
  {
    float* o0 = (i ? hat2 : hat1) + n * C_CH * HW_SZ;
    float* o1 = (i ? pt2 : pt1) + n * C_CH * HW_SZ;
    float* o2 = q2 + (i * 2 + n) * C_CH * HW_SZ;
    float* o3 = q3 + (i * 2 + n) * C_CH * HW_SZ;
    out = (ph == 0) ? o0 : (ph == 1) ? o1 : (ph == 2) ? o2 : o3;
  }

  __shared__ __align__(16) unsigned short fsA[2][128 * 64];  // 16KB each: [c][p swz]
  __shared__ __align__(16) unsigned short vB[2][64 * 32];    // 4KB each: [p][k swz]
  __shared__ __align__(16) unsigned short aT[256 * 64];      // 32KB: [q][p swz]

  const int wv = t >> 6, l = t & 63;
  const int g4 = l >> 4, lr16 = l & 15;      // d-gen (16x16)
  const int g2 = l >> 5, lr32 = l & 31;      // main (32x32)

  // mmain: wave -> c rows [cblk*64,+64), q cols [qblk*64,+64)
  const int cblk = wv & 1, qblk = wv >> 1;
  // dgen: wave -> q-frags j=0,1 at q = wv*32 + j*16; all 4 p-frags

  // ---- one-time u fragments (k-pad zeroed at source)
  const bf16x8 ub0 = *reinterpret_cast<const bf16x8*>(&uT[(q0 + wv * 32 + lr16) * 32 + g4 * 8]);
  const bf16x8 ub1 = *reinterpret_cast<const bf16x8*>(&uT[(q0 + wv * 32 + 16 + lr16) * 32 + g4 * 8]);

  f32x16 acc00, acc01, acc10, acc11;         // [cf][qf]
  #pragma unroll
  for (int r = 0; r < 16; ++r){ acc00[r] = 0.f; acc01[r] = 0.f; acc10[r] = 0.f; acc11[r] = 0.f; }
  const f32x4 zz = {0.f, 0.f, 0.f, 0.f};

  // ---- per-thread byte offsets (computed once)
  // fsA swizzle: row c (local 0..127), 8 slots of 16B; slot = u ^ (c&7) ^ b3<<2 ^ b4<<1
  int fs_src[2];
  #pragma unroll
  for (int it = 0; it < 2; ++it){
    int d = it * 512 + t; int c = d >> 3, sl = d & 7;
    int u = sl ^ (c & 7) ^ (((c >> 3) & 1) << 2) ^ (((c >> 4) & 1) << 1);
    fs_src[it] = (c0 + c) * (HW_SZ * 2) + u * 16;   // + P*2 per chunk
  }
  // vB: chunk j holds src k-unit u = (j&3) ^ (p&3) ^ ((p>>2)&3), p = j>>2
  int vt_src;
  {
    int j = t & 255; int p = j >> 2, sl = j & 3;
    int u = sl ^ (p & 3) ^ ((p >> 2) & 3);
    vt_src = p * 64 + u * 16;
  }
  // dgen vB read: row p = pf*16 + lr16 -> +pf*1024; slot pf-invariant
  int vbr0;
  {
    int p = lr16;
    vbr0 = p * 64 + ((g4 ^ (p & 3) ^ ((p >> 2) & 3)) << 4);
  }
  // dgen aT writes: q = wv*32 + j*16 + lr16; chunk = pf*2+(g4>>1) -> byte ^ (pf<<5)
  unsigned atw00, atw01;
  {
    int qd = wv * 32 + lr16;
    int sw = (g4 >> 1) ^ (qd & 7) ^ (((qd >> 3) & 1) << 2) ^ (((qd >> 4) & 1) << 1);
    atw00 = qd * 128 + sw * 16 + (g4 & 1) * 8;
    atw01 = (atw00 + 2048) ^ 32;               // q+16: row+2048, slot bit1 flips
  }
  // mmain reads: logical chunk = ks*2 + g2 -> base offset ^ (ks<<5)
  unsigned afo[2], bqo[2];
  #pragma unroll
  for (int cf = 0; cf < 2; ++cf){
    int crow = cblk * 64 + cf * 32 + lr32;
    afo[cf] = crow * 128 +
      ((g2 ^ (crow & 7) ^ (((crow >> 3) & 1) << 2) ^ (((crow >> 4) & 1) << 1)) << 4);
  }
  #pragma unroll
  for (int qf = 0; qf < 2; ++qf){
    int qrow = qblk * 64 + qf * 32 + lr32;
    bqo[qf] = qrow * 128 +
      ((g2 ^ (qrow & 7) ^ (((qrow >> 3) & 1) << 2) ^ (((qrow >> 4) & 1) << 1)) << 4);
  }

  const char* fsb[2] = {(const char*)&fsA[0][0], (const char*)&fsA[1][0]};
  const char* vbb[2] = {(const char*)&vB[0][0], (const char*)&vB[1][0]};
  char* atb = (char*)&aT[0];

  auto stage_fs = [&](unsigned short* dstbase, int p0){
    const char* src = (const char*)fs + p0 * 2;
    #pragma unroll
    for (int it = 0; it < 2; ++it)
      gload16(src + fs_src[it], dstbase + (it * 512 + wv * 64) * 8);
  };
  auto stage_v = [&](unsigned short* dstbase, int p0){
    if (wv < 4)
      gload16((const char*)vT + p0 * 64 + vt_src, dstbase + wv * 512);
  };
  auto dgen = [&](const char* vbB){
    #pragma unroll
    for (int pf = 0; pf < 4; ++pf){
      bf16x8 av = *reinterpret_cast<const bf16x8*>(vbB + vbr0 + pf * 1024);
      f32x4 d0 = __builtin_amdgcn_mfma_f32_16x16x32_bf16(av, ub0, zz, 0, 0, 0);
      f32x4 d1 = __builtin_amdgcn_mfma_f32_16x16x32_bf16(av, ub1, zz, 0, 0, 0);
      uint2 pk0, pk1;
      pk0.x = cvtpk(tanh_fast(d0[0]), tanh_fast(d0[1]));
      pk0.y = cvtpk(tanh_fast(d0[2]), tanh_fast(d0[3]));
      pk1.x = cvtpk(tanh_fast(d1[0]), tanh_fast(d1[1]));
      pk1.y = cvtpk(tanh_fast(d1[2]), tanh_fast(d1[3]));
      *reinterpret_cast<uint2*>(atb + (atw00 ^ (unsigned)(pf << 5))) = pk0;
      *reinterpret_cast<uint2*>(atb + (atw01 ^ (unsigned)(pf << 5))) = pk1;
    }
  };
  auto mmain = [&](const char* faB){
    #pragma unroll
    for (int ks = 0; ks < 4; ++ks){
      unsigned kx = (unsigned)(ks << 5);
      bf16x8 a0 = *reinterpret_cast<const bf16x8*>(faB + (afo[0] ^ kx));
      bf16x8 a1 = *reinterpret_cast<const bf16x8*>(faB + (afo[1] ^ kx));
      bf16x8 b0 = *reinterpret_cast<const bf16x8*>(atb + (bqo[0] ^ kx));
      bf16x8 b1 = *reinterpret_cast<const bf16x8*>(atb + (bqo[1] ^ kx));
      acc00 = __builtin_amdgcn_mfma_f32_32x32x16_bf16(a0, b0, acc00, 0, 0, 0);
      acc01 = __builtin_amdgcn_mfma_f32_32x32x16_bf16(a0, b1, acc01, 0, 0, 0);
      acc10 = __builtin_amdgcn_mfma_f32_32x32x16_bf16(a1, b0, acc10, 0, 0, 0);
      acc11 = __builtin_amdgcn_mfma_f32_32x32x16_bf16(a1, b1, acc11, 0, 0, 0);
    }
  };

  // ---- prologue: chunk 0 into buf 0
  stage_fs(fsA[0], pbase);
  stage_v(vB[0], pbase);
  __syncthreads();

  // ---- main loop: 16 chunks, unrolled x2 (compile-time buffers).
  // Final prefetch overreads <=64 cols into adjacent ws buffers (allocated; harmless).
  #pragma unroll 1
  for (int k2 = 0; k2 < 8; ++k2){
    {
      stage_fs(fsA[1], pbase + (2 * k2 + 1) * 64);
      stage_v(vB[1], pbase + (2 * k2 + 1) * 64);
      dgen(vbb[0]);
      asm volatile("s_waitcnt lgkmcnt(0)" ::: "memory");
      __builtin_amdgcn_sched_barrier(0);
      __builtin_amdgcn_s_barrier();           // aT visible; DMA still in flight
      mmain(fsb[0]);
      __syncthreads();                        // drains vmcnt (latency covered by compute)
    }
    {
      stage_fs(fsA[0], pbase + (2 * k2 + 2) * 64);
      stage_v(vB[0], pbase + (2 * k2 + 2) * 64);
      dgen(vbb[1]);
      asm volatile("s_waitcnt lgkmcnt(0)" ::: "memory");
      __builtin_amdgcn_sched_barrier(0);
      __builtin_amdgcn_s_barrier();
      mmain(fsb[1]);
      __syncthreads();
    }
  }

  // ---- store: 32x32 C-layout: col(=q)=lane&31, row(=c)=(reg&3)+8*(reg>>2)+4*(lane>>5)
  const int qcol = q0 + qblk * 64 + lr32;
  const int cbase = c0 + cblk * 64;
  #pragma unroll
  for (int r = 0; r < 16; ++r){
    int cr = (r & 3) + 8 * (r >> 2) + 4 * g2;
    out[(cbase + cr) * HW_SZ + qcol] = acc00[r];
    out[(cbase + cr) * HW_SZ + qcol + 32] = acc01[r];
    out[(cbase + 32 + cr) * HW_SZ + qcol] = acc10[r];
    out[(cbase + 32 + cr) * HW_SZ + qcol + 32] = acc11[r];
  }
}

// ---------- l2norm(channels) of (p0+p1+p2+p3) + residual + relu (in-place into p0) + stage-2 conv
__global__ void k_norm(float* __restrict__ hat1, float* __restrict__ hat2,
                       const float* __restrict__ pt1, const float* __restrict__ pt2,
                       const float* __restrict__ q2, const float* __restrict__ q3,
                       const float* __restrict__ f1, const float* __restrict__ f2,
                       const float* __restrict__ cw1, const float* __restrict__ cw2,
                       const float* __restrict__ cb1, const float* __restrict__ cb2,
                       float* __restrict__ cv2){
  const int i = blockIdx.z, n = blockIdx.y, t = threadIdx.x;
  const int ql = t & 63, cg = t >> 6;
  const int q = blockIdx.x * 64 + ql;
  float* hat = (i ? hat2 : hat1) + n * C_CH * HW_SZ;
  const float* pt = (i ? pt2 : pt1) + n * C_CH * HW_SZ;
  const float* p2 = q2 + (i * 2 + n) * C_CH * HW_SZ;
  const float* p3 = q3 + (i * 2 + n) * C_CH * HW_SZ;
  const float* f = (i ? f2 : f1) + n * C_CH * HW_SZ;
  __shared__ float ws[C_CH];
  __shared__ float red[4][72];
  __shared__ float invs[64];
  ws[t] = (i ? cw2 : cw1)[t];
  __syncthreads();
  float s = 0.f;
  #pragma unroll 8
  for (int c = cg * 64; c < cg * 64 + 64; ++c){
    int idx = c * HW_SZ + q;
    float h = (hat[idx] + pt[idx]) + (p2[idx] + p3[idx]);
    s += h * h;
  }
  red[cg][ql] = s; __syncthreads();
  if (t < 64){
    float ss = red[0][t] + red[1][t] + red[2][t] + red[3][t];
    invs[t] = 1.0f / fmaxf(sqrtf(ss), 1e-12f);
  }
  __syncthreads();
  const float inv = invs[ql];
  float ca = 0.f;
  #pragma unroll 8
  for (int c = cg * 64; c < cg * 64 + 64; ++c){
    int idx = c * HW_SZ + q;
    float h = (hat[idx] + pt[idx]) + (p2[idx] + p3[idx]);
    float vv = fmaxf(h * inv + f[idx], 0.0f);
    hat[idx] = vv;  // in-place: only this thread touches [c][q]
    ca += ws[c] * vv;
  }
  red[cg][ql] = ca; __syncthreads();
  if (t < 64){
    float ss = red[0][t] + red[1][t] + red[2][t] + red[3][t] + (i ? cb2[0] : cb1[0]);
    cv2[(i * 2 + n) * HW_SZ + blockIdx.x * 64 + t] = ss;
  }
}

// ---------- final: out_i = pr2_i * fp_i
__global__ void k_final(const float* __restrict__ fp1, const float* __restrict__ fp2,
                        const float* __restrict__ pr2, float* __restrict__ outp){
  const int i = blockIdx.z;
  const int idx4 = (blockIdx.x * 256 + threadIdx.x) * 4;
  const int n = idx4 >> 20;
  const int q = idx4 & (HW_SZ - 1);
  const float* fp = i ? fp2 : fp1;
  float4 vv = *reinterpret_cast<const float4*>(&fp[idx4]);
  float4 pp = *reinterpret_cast<const float4*>(&pr2[(i * 2 + n) * HW_SZ + q]);
  float4 o; o.x = vv.x * pp.x; o.y = vv.y * pp.y; o.z = vv.z * pp.z; o.w = vv.w * pp.w;
  *reinterpret_cast<float4*>(&outp[i * (C_CH * HW_SZ * N_B) + idx4]) = o;
}

extern "C" void kernel_launch(void* const* d_in, const int* in_sizes, int n_in,
                              void* d_out, int out_size, void* d_ws, size_t ws_size,
                              hipStream_t stream){
  const float* f1  = (const float*)d_in[0];
  const float* f2  = (const float*)d_in[1];
  const float* pw1 = (const float*)d_in[2];
  const float* pb1 = (const float*)d_in[3];
  const float* pw2 = (const float*)d_in[4];
  const float* pb2 = (const float*)d_in[5];
  const float* cw1 = (const float*)d_in[6];
  const float* cb1 = (const float*)d_in[7];
  const float* cw2 = (const float*)d_in[8];
  const float* cb2 = (const float*)d_in[9];
  float* ws = (float*)d_ws;
  float* outp = (float*)d_out;
  // layout (float offsets): HAT = part0 (doubles as FP), PT = part1,
  // part2 -> d_out (dead until k_final), part3 -> Q3.
  float* HAT1 = ws;                                        // 2,097,152 floats each
  float* HAT2 = ws + 2097152;
  float* PT1  = ws + 4194304;
  float* PT2  = ws + 6291456;
  float* Q3   = ws + 8388608;                              // 4,194,304 floats, (i*2+n) major
  unsigned short* FS1 = (unsigned short*)(ws + 12582912);  // bf16 [C][HW] per n
  unsigned short* FS2 = (unsigned short*)(ws + 13631488);
  unsigned short* CLT1 = (unsigned short*)(ws + 14680064); // bf16 [HW][32] per n
  unsigned short* CLT2 = (unsigned short*)(ws + 14811136);
  float* CV1  = ws + 14942208;
  float* PR1  = ws + 14958592;
  float* CV2  = ws + 14974976;
  float* PR2  = ws + 14991360;                             // end 15,007,744 floats ~= 60.0 MiB
  float* Q2   = outp;                                      // part2 lives in d_out

  k_conv1   <<<dim3(64, 2, 2), 256, 0, stream>>>(f1, f2, cw1, cw2, cb1, cb2, CV1);
  k_softmax <<<4, 256, 0, stream>>>(CV1, PR1);
  k_scale_cl<<<dim3(64, 2, 2), 256, 0, stream>>>(f1, f2, PR1, pw1, pw2, pb1, pb2,
                                                 FS1, FS2, CLT1, CLT2);
  k_hat     <<<512, 512, 0, stream>>>(FS1, FS2, CLT1, CLT2, HAT1, HAT2, PT1, PT2, Q2, Q3);
  k_norm    <<<dim3(64, 2, 2), 256, 0, stream>>>(HAT1, HAT2, PT1, PT2, Q2, Q3, f1, f2,
                                                 cw1, cw2, cb1, cb2, CV2);
  k_softmax <<<4, 256, 0, stream>>>(CV2, PR2);
  k_final   <<<dim3(2048, 1, 2), 256, 0, stream>>>(HAT1, HAT2, PR2, outp);
}

// Round 10
// 107.690 us; speedup vs baseline: 1.4212x; 1.4212x over previous
//
#include <hip/hip_runtime.h>
#include <hip/hip_bf16.h>
#include <math.h>

#define N_B 2
#define C_CH 256
#define HW_SZ 4096
#define CL_CH 16

typedef __bf16 bf16x8 __attribute__((ext_vector_type(8)));
typedef float f32x4 __attribute__((ext_vector_type(4)));
typedef float f32x16 __attribute__((ext_vector_type(16)));

__device__ __forceinline__ unsigned short f2bf(float x){
  __hip_bfloat16 b = __float2bfloat16(x);   // RTNE
  return *reinterpret_cast<unsigned short*>(&b);
}
// packed f32x2 -> bf16x2 (single v_cvt_pk_bf16_f32)
__device__ __forceinline__ unsigned int cvtpk(float a, float b){
  unsigned int r;
  asm("v_cvt_pk_bf16_f32 %0, %1, %2" : "=v"(r) : "v"(a), "v"(b));
  return r;
}
// tanh = 1 - 2*rcp(1+e^{2x}); NaN-safe at +-inf; rcp err ~1e-7 (<< bf16 ulp)
__device__ __forceinline__ float tanh_fast(float x){
  float e = __expf(2.0f * x);
  return fmaf(-2.0f, __builtin_amdgcn_rcpf(1.0f + e), 1.0f);
}
// async global->LDS, 16B per lane; dst must be wave-uniform base (+lane*16 implicit)
__device__ __forceinline__ void gload16(const void* gsrc, void* lds_dst){
  __builtin_amdgcn_global_load_lds(
      (const __attribute__((address_space(1))) unsigned int*)gsrc,
      (__attribute__((address_space(3))) unsigned int*)lds_dst, 16, 0, 0);
}

// ---------- Stage-1 conv (C->1)
__global__ void k_conv1(const float* __restrict__ f1, const float* __restrict__ f2,
                        const float* __restrict__ w1, const float* __restrict__ w2,
                        const float* __restrict__ b1, const float* __restrict__ b2,
                        float* __restrict__ cv){
  const int i = blockIdx.z, n = blockIdx.y, t = threadIdx.x;
  const int ql = t & 63, cg = t >> 6;
  const int q = blockIdx.x * 64 + ql;
  const float* f = (i ? f2 : f1) + n * C_CH * HW_SZ;
  const float* w = i ? w2 : w1;
  __shared__ float ws[C_CH];
  __shared__ float red[4][72];
  ws[t] = w[t];
  __syncthreads();
  float acc = 0.f;
  #pragma unroll 8
  for (int c = cg * 64; c < cg * 64 + 64; ++c)
    acc += f[c * HW_SZ + q] * ws[c];
  red[cg][ql] = acc;
  __syncthreads();
  if (t < 64){
    float s = red[0][t] + red[1][t] + red[2][t] + red[3][t] + (i ? b2[0] : b1[0]);
    cv[(i * 2 + n) * HW_SZ + blockIdx.x * 64 + t] = s;
  }
}

// ---------- softmax over 4096 per row; grid(4) block 256
__global__ void k_softmax(const float* __restrict__ cv, float* __restrict__ pr){
  const int r = blockIdx.x, t = threadIdx.x;
  const float* x = cv + r * HW_SZ;
  float* y = pr + r * HW_SZ;
  __shared__ float red[256];
  float v[16];
  float m = -1e30f;
  #pragma unroll
  for (int j = 0; j < 16; j++){ v[j] = x[j * 256 + t]; m = fmaxf(m, v[j]); }
  red[t] = m; __syncthreads();
  for (int s = 128; s > 0; s >>= 1){ if (t < s) red[t] = fmaxf(red[t], red[t + s]); __syncthreads(); }
  m = red[0]; __syncthreads();
  float sum = 0.f;
  #pragma unroll
  for (int j = 0; j < 16; j++){ v[j] = __expf(v[j] - m); sum += v[j]; }
  red[t] = sum; __syncthreads();
  for (int s = 128; s > 0; s >>= 1){ if (t < s) red[t] += red[t + s]; __syncthreads(); }
  const float inv = 1.0f / red[0];
  #pragma unroll
  for (int j = 0; j < 16; j++) y[j * 256 + t] = v[j] * inv;
}

// ---------- fs_i = bf16(pr_i * f_i) ; clT_i[q][0..15] = bf16(pw_i @ (pr*f) + pb_i),
// clT rows 32 wide, k in [16,32) zeroed (branch-free MFMA fragments in k_hat)
__global__ void k_scale_cl(const float* __restrict__ f1, const float* __restrict__ f2,
                           const float* __restrict__ pr,
                           const float* __restrict__ pw1, const float* __restrict__ pw2,
                           const float* __restrict__ pb1, const float* __restrict__ pb2,
                           unsigned short* __restrict__ fs1, unsigned short* __restrict__ fs2,
                           unsigned short* __restrict__ clT1, unsigned short* __restrict__ clT2){
  const int i = blockIdx.z, n = blockIdx.y, t = threadIdx.x;
  const int ql = t & 63, cg = t >> 6;
  const int q = blockIdx.x * 64 + ql;
  const float* f = (i ? f2 : f1) + n * C_CH * HW_SZ;
  unsigned short* fs = (i ? fs2 : fs1) + n * C_CH * HW_SZ;
  unsigned short* clT = (i ? clT2 : clT1) + n * 32 * HW_SZ;
  const float* pw = i ? pw2 : pw1;
  const float* pb = i ? pb2 : pb1;
  __shared__ float wls[CL_CH * C_CH];
  __shared__ float red[4][CL_CH][66];
  #pragma unroll
  for (int j = 0; j < 16; j++) wls[j * 256 + t] = pw[j * 256 + t];
  __syncthreads();
  const float p = pr[(i * 2 + n) * HW_SZ + q];
  float acc[16];
  #pragma unroll
  for (int k = 0; k < 16; k++) acc[k] = 0.f;
  for (int c = cg * 64; c < cg * 64 + 64; ++c){
    float vv = f[c * HW_SZ + q] * p;
    fs[c * HW_SZ + q] = f2bf(vv);
    #pragma unroll
    for (int k = 0; k < 16; k++) acc[k] += wls[k * 256 + c] * vv;
  }
  #pragma unroll
  for (int k = 0; k < 16; k++) red[cg][k][ql] = acc[k];
  __syncthreads();
  #pragma unroll
  for (int j = 0; j < 4; j++){
    int e = j * 256 + t; int k = e >> 6, qq = e & 63;
    float s = red[0][k][qq] + red[1][k][qq] + red[2][k][qq] + red[3][k][qq] + pb[k];
    clT[(blockIdx.x * 64 + qq) * 32 + k] = f2bf(s);
  }
  // zero the k in [16,32) pad
  if (t < 128){
    uint4 zv = {0u, 0u, 0u, 0u};
    int qq = t >> 1, half = t & 1;
    *reinterpret_cast<uint4*>(&clT[(blockIdx.x * 64 + qq) * 32 + 16 + half * 8]) = zv;
  }
}

// ---------- fused hat GEMM via MFMA. C=256 x Q=64 tile, split-K over p-halves.
// Single-barrier fused-phase chunks: {fs-DMA(k+1), v-regs(k+2), dgen(k+1)->aT[alt],
// mmain(k), syncthreads}. v lives in registers (global loads), aT double-buffered.
// grid 512 (XCD-swizzled), block 512 (8 waves), LDS 80KB -> 2 blk/CU.
__global__ __launch_bounds__(512, 4) void k_hat(
    const unsigned short* __restrict__ fs1, const unsigned short* __restrict__ fs2,
    const unsigned short* __restrict__ clT1, const unsigned short* __restrict__ clT2,
    float* __restrict__ hat1, float* __restrict__ hat2,
    float* __restrict__ pt1, float* __restrict__ pt2){
  const int t = threadIdx.x;
  const int bid = blockIdx.x;
  const int xcd = bid & 7, slot = bid >> 3;  // slot 0..63
  const int z = xcd >> 1;                    // 0..3 -> (n,i); 2 XCDs per (n,i)
  const int n = z & 1, i = z >> 1;
  const int x = slot * 2 + (xcd & 1);        // 0..127
  const int qt = x >> 1, ph = x & 1;         // 64 q-tiles x 2 p-halves
  const int q0 = qt * 64;
  const int pbase = ph * 2048;

  const unsigned short* fs = (i ? fs2 : fs1) + n * C_CH * HW_SZ;
  const unsigned short* uT = (i ? clT1 : clT2) + n * 32 * HW_SZ;  // q-side [HW][32]
  const unsigned short* vT = (i ? clT2 : clT1) + n * 32 * HW_SZ;  // p-side [HW][32]
  float* out = (ph ? (i ? pt2 : pt1) : (i ? hat2 : hat1)) + n * C_CH * HW_SZ;

  __shared__ __align__(16) unsigned short fsA[2][C_CH * 64];  // 32KB each: [c][p swz]
  __shared__ __align__(16) unsigned short aT[2][64 * 64];     // 8KB each: [q][p swz]

  const int wv = t >> 6, l = t & 63;
  const int g4 = l >> 4, lr16 = l & 15;      // d-gen (16x16)
  const int g2 = l >> 5, lr32 = l & 31;      // main (32x32)

  const int pfw = wv & 3;                    // dgen p-frag
  const int qf0 = (wv >> 2) * 2;             // dgen q-frags qf0, qf0+1
  const int cblk = wv & 3, qblk = wv >> 2;   // mmain: c rows [cblk*64,+64), q [qblk*32,+32)

  // ---- one-time u fragments (k-pad zeroed at source)
  const bf16x8 ub0 = *reinterpret_cast<const bf16x8*>(&uT[(q0 + qf0 * 16 + lr16) * 32 + g4 * 8]);
  const bf16x8 ub1 = *reinterpret_cast<const bf16x8*>(&uT[(q0 + qf0 * 16 + 16 + lr16) * 32 + g4 * 8]);

  f32x16 acc0, acc1;
  #pragma unroll
  for (int r = 0; r < 16; ++r){ acc0[r] = 0.f; acc1[r] = 0.f; }
  const f32x4 zz = {0.f, 0.f, 0.f, 0.f};

  // ---- per-thread byte offsets (computed once)
  // fsA: LDS chunk d holds src col16 u = (d&7) ^ (c&7) ^ (((c>>3)&1)<<2), c = d>>3
  int fs_src[4];
  #pragma unroll
  for (int it = 0; it < 4; ++it){
    int d = it * 512 + t; int c = d >> 3, sl = d & 7;
    int u = sl ^ (c & 7) ^ (((c >> 3) & 1) << 2);
    fs_src[it] = c * (HW_SZ * 2) + u * 16;
  }
  // v global source (per-lane register load, bf16x8 = 16B)
  const char* vbase = (const char*)vT;
  const int vgo = (pfw * 16 + lr16) * 64 + g4 * 16;  // bytes within chunk
  // dgen aT write: q = qf0*16+lr16 (+16 for frag1); chunk id = pfw*2+(g4>>1)
  unsigned atw0;
  {
    int qd = qf0 * 16 + lr16;
    int sw = (pfw * 2 + (g4 >> 1)) ^ (qd & 7) ^ (((qd >> 3) & 1) << 2);
    atw0 = qd * 128 + sw * 16 + (g4 & 1) * 8;        // +2048 for q+16 (swz bits unchanged)
  }
  // mmain reads: logical chunk = ks*2 + g2 -> base offset ^ (ks<<5)
  unsigned afo[2], bqo;
  #pragma unroll
  for (int cf = 0; cf < 2; ++cf){
    int crow = cblk * 64 + cf * 32 + lr32;
    afo[cf] = crow * 128 + ((g2 ^ (crow & 7) ^ (((crow >> 3) & 1) << 2)) << 4);
  }
  {
    int qrow = qblk * 32 + lr32;
    bqo = qrow * 128 + ((g2 ^ (qrow & 7) ^ (((qrow >> 3) & 1) << 2)) << 4);
  }

  auto vload = [&](int kk) -> uint4 {
    return *reinterpret_cast<const uint4*>(vbase + (pbase + kk * 64) * 64 + vgo);
  };
  auto stage_fs = [&](unsigned short* dstbase, int p0){
    const char* src = (const char*)fs + p0 * 2;
    #pragma unroll
    for (int it = 0; it < 4; ++it)
      gload16(src + fs_src[it], dstbase + (it * 512 + wv * 64) * 8);
  };
  auto dgen = [&](uint4 vr, char* atB){
    bf16x8 av = *reinterpret_cast<bf16x8*>(&vr);
    f32x4 d0 = __builtin_amdgcn_mfma_f32_16x16x32_bf16(av, ub0, zz, 0, 0, 0);
    f32x4 d1 = __builtin_amdgcn_mfma_f32_16x16x32_bf16(av, ub1, zz, 0, 0, 0);
    uint2 pk0, pk1;
    pk0.x = cvtpk(tanh_fast(d0[0]), tanh_fast(d0[1]));
    pk0.y = cvtpk(tanh_fast(d0[2]), tanh_fast(d0[3]));
    pk1.x = cvtpk(tanh_fast(d1[0]), tanh_fast(d1[1]));
    pk1.y = cvtpk(tanh_fast(d1[2]), tanh_fast(d1[3]));
    *reinterpret_cast<uint2*>(atB + atw0) = pk0;
    *reinterpret_cast<uint2*>(atB + atw0 + 2048) = pk1;
  };
  auto mmain = [&](const char* faB, const char* atB){
    #pragma unroll
    for (int ks = 0; ks < 4; ++ks){
      unsigned kx = (unsigned)(ks << 5);
      bf16x8 b0 = *reinterpret_cast<const bf16x8*>(atB + (bqo ^ kx));
      bf16x8 a0 = *reinterpret_cast<const bf16x8*>(faB + (afo[0] ^ kx));
      bf16x8 a1 = *reinterpret_cast<const bf16x8*>(faB + (afo[1] ^ kx));
      acc0 = __builtin_amdgcn_mfma_f32_32x32x16_bf16(a0, b0, acc0, 0, 0, 0);
      acc1 = __builtin_amdgcn_mfma_f32_32x32x16_bf16(a1, b0, acc1, 0, 0, 0);
    }
  };

  // ---- prologue: v(0),v(1) in regs; fs chunk0 DMA; a(0) -> aT[0]
  uint4 va = vload(0);
  uint4 vb = vload(1);
  stage_fs(fsA[0], pbase);
  dgen(va, (char*)aT[0]);
  __syncthreads();                            // aT[0] + fsA[0] ready

  // ---- main loop: 32 chunks, one barrier per chunk, unrolled x2 (static buffers).
  // Tail overreads (fs chunk 32, v chunks 33/34; final wasted dgen) land in
  // allocated ws regions / dead buffers -- harmless by construction.
  #pragma unroll 1
  for (int k2 = 0; k2 < 16; ++k2){
    {
      const int k = 2 * k2;
      stage_fs(fsA[1], pbase + (k + 1) * 64);   // DMA next chunk (in flight past dgen/mmain)
      va = vload(k + 2);                        // v for chunk k+2 (used next sub-chunk)
      dgen(vb, (char*)aT[1]);                   // a(k+1), pure reg/MFMA/VALU
      mmain((const char*)fsA[0], (const char*)aT[0]);
      __syncthreads();
    }
    {
      const int k = 2 * k2 + 1;
      stage_fs(fsA[0], pbase + (k + 1) * 64);
      vb = vload(k + 2);
      dgen(va, (char*)aT[0]);
      mmain((const char*)fsA[1], (const char*)aT[1]);
      __syncthreads();
    }
  }

  // ---- store: 32x32 C-layout: col(=q)=lane&31, row(=c)=(reg&3)+8*(reg>>2)+4*(lane>>5)
  const int qcol = q0 + qblk * 32 + lr32;
  #pragma unroll
  for (int r = 0; r < 16; ++r){
    int cr = (r & 3) + 8 * (r >> 2) + 4 * g2;
    out[(cblk * 64 + cr) * HW_SZ + qcol] = acc0[r];
    out[(cblk * 64 + 32 + cr) * HW_SZ + qcol] = acc1[r];
  }
}

// ---------- l2norm(channels) of (part0+part1) + residual + relu (in-place into part0)
// + stage-2 conv. Single-pass: h cached in 32 regs/thread (hat/pt read ONCE).
// grid(128, 2, 2) block 256: 32 q x 8 c-groups of 32.
__global__ void k_norm(float* __restrict__ hat1, float* __restrict__ hat2,
                       const float* __restrict__ pt1, const float* __restrict__ pt2,
                       const float* __restrict__ f1, const float* __restrict__ f2,
                       const float* __restrict__ cw1, const float* __restrict__ cw2,
                       const float* __restrict__ cb1, const float* __restrict__ cb2,
                       float* __restrict__ cv2){
  const int i = blockIdx.z, n = blockIdx.y, t = threadIdx.x;
  const int ql = t & 31, cg = t >> 5;
  const int q = blockIdx.x * 32 + ql;
  float* hat = (i ? hat2 : hat1) + n * C_CH * HW_SZ;
  const float* pt = (i ? pt2 : pt1) + n * C_CH * HW_SZ;
  const float* f = (i ? f2 : f1) + n * C_CH * HW_SZ;
  __shared__ float ws[C_CH];
  __shared__ float red[8][36];
  __shared__ float invs[32];
  ws[t] = (i ? cw2 : cw1)[t];
  __syncthreads();
  float hc[32];
  float s = 0.f;
  #pragma unroll
  for (int j = 0; j < 32; ++j){
    int c = cg * 32 + j;
    float h = hat[c * HW_SZ + q] + pt[c * HW_SZ + q];
    hc[j] = h;
    s += h * h;
  }
  red[cg][ql] = s; __syncthreads();
  if (t < 32){
    float ss = 0.f;
    #pragma unroll
    for (int g = 0; g < 8; ++g) ss += red[g][t];
    invs[t] = 1.0f / fmaxf(sqrtf(ss), 1e-12f);
  }
  __syncthreads();
  const float inv = invs[ql];
  float ca = 0.f;
  #pragma unroll
  for (int j = 0; j < 32; ++j){
    int c = cg * 32 + j;
    float vv = fmaxf(hc[j] * inv + f[c * HW_SZ + q], 0.0f);
    hat[c * HW_SZ + q] = vv;  // in-place: only this thread touches [c][q]
    ca += ws[c] * vv;
  }
  red[cg][ql] = ca; __syncthreads();
  if (t < 32){
    float ss = (i ? cb2[0] : cb1[0]);
    #pragma unroll
    for (int g = 0; g < 8; ++g) ss += red[g][t];
    cv2[(i * 2 + n) * HW_SZ + blockIdx.x * 32 + t] = ss;
  }
}

// ---------- final: out_i = pr2_i * fp_i
__global__ void k_final(const float* __restrict__ fp1, const float* __restrict__ fp2,
                        const float* __restrict__ pr2, float* __restrict__ outp){
  const int i = blockIdx.z;
  const int idx4 = (blockIdx.x * 256 + threadIdx.x) * 4;
  const int n = idx4 >> 20;
  const int q = idx4 & (HW_SZ - 1);
  const float* fp = i ? fp2 : fp1;
  float4 vv = *reinterpret_cast<const float4*>(&fp[idx4]);
  float4 pp = *reinterpret_cast<const float4*>(&pr2[(i * 2 + n) * HW_SZ + q]);
  float4 o; o.x = vv.x * pp.x; o.y = vv.y * pp.y; o.z = vv.z * pp.z; o.w = vv.w * pp.w;
  *reinterpret_cast<float4*>(&outp[i * (C_CH * HW_SZ * N_B) + idx4]) = o;
}

extern "C" void kernel_launch(void* const* d_in, const int* in_sizes, int n_in,
                              void* d_out, int out_size, void* d_ws, size_t ws_size,
                              hipStream_t stream){
  const float* f1  = (const float*)d_in[0];
  const float* f2  = (const float*)d_in[1];
  const float* pw1 = (const float*)d_in[2];
  const float* pb1 = (const float*)d_in[3];
  const float* pw2 = (const float*)d_in[4];
  const float* pb2 = (const float*)d_in[5];
  const float* cw1 = (const float*)d_in[6];
  const float* cb1 = (const float*)d_in[7];
  const float* cw2 = (const float*)d_in[8];
  const float* cb2 = (const float*)d_in[9];
  float* ws = (float*)d_ws;
  // layout (float offsets): HAT = part0 (doubles as FP), PT = part1
  float* HAT1 = ws;                                        // 2,097,152 floats each
  float* HAT2 = ws + 2097152;
  float* PT1  = ws + 4194304;
  float* PT2  = ws + 6291456;
  unsigned short* FS1 = (unsigned short*)(ws + 8388608);   // bf16 [C][HW] per n
  unsigned short* FS2 = (unsigned short*)(ws + 9437184);
  unsigned short* CLT1 = (unsigned short*)(ws + 10485760); // bf16 [HW][32] per n
  unsigned short* CLT2 = (unsigned short*)(ws + 10616832);
  float* CV1  = ws + 10747904;
  float* PR1  = ws + 10764288;
  float* CV2  = ws + 10780672;
  float* PR2  = ws + 10797056;                             // end 10,813,440 floats ~= 43.3 MiB
  float* outp = (float*)d_out;

  k_conv1   <<<dim3(64, 2, 2), 256, 0, stream>>>(f1, f2, cw1, cw2, cb1, cb2, CV1);
  k_softmax <<<4, 256, 0, stream>>>(CV1, PR1);
  k_scale_cl<<<dim3(64, 2, 2), 256, 0, stream>>>(f1, f2, PR1, pw1, pw2, pb1, pb2,
                                                 FS1, FS2, CLT1, CLT2);
  k_hat     <<<512, 512, 0, stream>>>(FS1, FS2, CLT1, CLT2, HAT1, HAT2, PT1, PT2);
  k_norm    <<<dim3(128, 2, 2), 256, 0, stream>>>(HAT1, HAT2, PT1, PT2, f1, f2,
                                                  cw1, cw2, cb1, cb2, CV2);
  k_softmax <<<4, 256, 0, stream>>>(CV2, PR2);
  k_final   <<<dim3(2048, 1, 2), 256, 0, stream>>>(HAT1, HAT2, PR2, outp);
}

// Round 11
// 105.363 us; speedup vs baseline: 1.4525x; 1.0221x over previous
//
#include <hip/hip_runtime.h>
#include <hip/hip_bf16.h>
#include <math.h>

#define N_B 2
#define C_CH 256
#define HW_SZ 4096
#define CL_CH 16

typedef __bf16 bf16x8 __attribute__((ext_vector_type(8)));
typedef float f32x4 __attribute__((ext_vector_type(4)));
typedef float f32x16 __attribute__((ext_vector_type(16)));

__device__ __forceinline__ unsigned short f2bf(float x){
  __hip_bfloat16 b = __float2bfloat16(x);   // RTNE
  return *reinterpret_cast<unsigned short*>(&b);
}
// packed f32x2 -> bf16x2 (single v_cvt_pk_bf16_f32)
__device__ __forceinline__ unsigned int cvtpk(float a, float b){
  unsigned int r;
  asm("v_cvt_pk_bf16_f32 %0, %1, %2" : "=v"(r) : "v"(a), "v"(b));
  return r;
}
// tanh = 1 - 2*rcp(1+e^{2x}); NaN-safe at +-inf; rcp err ~1e-7 (<< bf16 ulp)
__device__ __forceinline__ float tanh_fast(float x){
  float e = __expf(2.0f * x);
  return fmaf(-2.0f, __builtin_amdgcn_rcpf(1.0f + e), 1.0f);
}
// async global->LDS, 16B per lane; dst must be wave-uniform base (+lane*16 implicit)
__device__ __forceinline__ void gload16(const void* gsrc, void* lds_dst){
  __builtin_amdgcn_global_load_lds(
      (const __attribute__((address_space(1))) unsigned int*)gsrc,
      (__attribute__((address_space(3))) unsigned int*)lds_dst, 16, 0, 0);
}

// ---------- Stage-1 conv (C->1)
__global__ void k_conv1(const float* __restrict__ f1, const float* __restrict__ f2,
                        const float* __restrict__ w1, const float* __restrict__ w2,
                        const float* __restrict__ b1, const float* __restrict__ b2,
                        float* __restrict__ cv){
  const int i = blockIdx.z, n = blockIdx.y, t = threadIdx.x;
  const int ql = t & 63, cg = t >> 6;
  const int q = blockIdx.x * 64 + ql;
  const float* f = (i ? f2 : f1) + n * C_CH * HW_SZ;
  const float* w = i ? w2 : w1;
  __shared__ float ws[C_CH];
  __shared__ float red[4][72];
  ws[t] = w[t];
  __syncthreads();
  float acc = 0.f;
  #pragma unroll 8
  for (int c = cg * 64; c < cg * 64 + 64; ++c)
    acc += f[c * HW_SZ + q] * ws[c];
  red[cg][ql] = acc;
  __syncthreads();
  if (t < 64){
    float s = red[0][t] + red[1][t] + red[2][t] + red[3][t] + (i ? b2[0] : b1[0]);
    cv[(i * 2 + n) * HW_SZ + blockIdx.x * 64 + t] = s;
  }
}

// ---------- softmax over 4096 per row; grid(4) block 256
__global__ void k_softmax(const float* __restrict__ cv, float* __restrict__ pr){
  const int r = blockIdx.x, t = threadIdx.x;
  const float* x = cv + r * HW_SZ;
  float* y = pr + r * HW_SZ;
  __shared__ float red[256];
  float v[16];
  float m = -1e30f;
  #pragma unroll
  for (int j = 0; j < 16; j++){ v[j] = x[j * 256 + t]; m = fmaxf(m, v[j]); }
  red[t] = m; __syncthreads();
  for (int s = 128; s > 0; s >>= 1){ if (t < s) red[t] = fmaxf(red[t], red[t + s]); __syncthreads(); }
  m = red[0]; __syncthreads();
  float sum = 0.f;
  #pragma unroll
  for (int j = 0; j < 16; j++){ v[j] = __expf(v[j] - m); sum += v[j]; }
  red[t] = sum; __syncthreads();
  for (int s = 128; s > 0; s >>= 1){ if (t < s) red[t] += red[t + s]; __syncthreads(); }
  const float inv = 1.0f / red[0];
  #pragma unroll
  for (int j = 0; j < 16; j++) y[j * 256 + t] = v[j] * inv;
}

// ---------- fs_i = bf16(pr_i * f_i) ; clT_i[q][0..15] = bf16(pw_i @ (pr*f) + pb_i),
// clT rows 32 wide, k in [16,32) zeroed (branch-free MFMA fragments in k_hat)
__global__ void k_scale_cl(const float* __restrict__ f1, const float* __restrict__ f2,
                           const float* __restrict__ pr,
                           const float* __restrict__ pw1, const float* __restrict__ pw2,
                           const float* __restrict__ pb1, const float* __restrict__ pb2,
                           unsigned short* __restrict__ fs1, unsigned short* __restrict__ fs2,
                           unsigned short* __restrict__ clT1, unsigned short* __restrict__ clT2){
  const int i = blockIdx.z, n = blockIdx.y, t = threadIdx.x;
  const int ql = t & 63, cg = t >> 6;
  const int q = blockIdx.x * 64 + ql;
  const float* f = (i ? f2 : f1) + n * C_CH * HW_SZ;
  unsigned short* fs = (i ? fs2 : fs1) + n * C_CH * HW_SZ;
  unsigned short* clT = (i ? clT2 : clT1) + n * 32 * HW_SZ;
  const float* pw = i ? pw2 : pw1;
  const float* pb = i ? pb2 : pb1;
  __shared__ float wls[CL_CH * C_CH];
  __shared__ float red[4][CL_CH][66];
  #pragma unroll
  for (int j = 0; j < 16; j++) wls[j * 256 + t] = pw[j * 256 + t];
  __syncthreads();
  const float p = pr[(i * 2 + n) * HW_SZ + q];
  float acc[16];
  #pragma unroll
  for (int k = 0; k < 16; k++) acc[k] = 0.f;
  for (int c = cg * 64; c < cg * 64 + 64; ++c){
    float vv = f[c * HW_SZ + q] * p;
    fs[c * HW_SZ + q] = f2bf(vv);
    #pragma unroll
    for (int k = 0; k < 16; k++) acc[k] += wls[k * 256 + c] * vv;
  }
  #pragma unroll
  for (int k = 0; k < 16; k++) red[cg][k][ql] = acc[k];
  __syncthreads();
  #pragma unroll
  for (int j = 0; j < 4; j++){
    int e = j * 256 + t; int k = e >> 6, qq = e & 63;
    float s = red[0][k][qq] + red[1][k][qq] + red[2][k][qq] + red[3][k][qq] + pb[k];
    clT[(blockIdx.x * 64 + qq) * 32 + k] = f2bf(s);
  }
  // zero the k in [16,32) pad
  if (t < 128){
    uint4 zv = {0u, 0u, 0u, 0u};
    int qq = t >> 1, half = t & 1;
    *reinterpret_cast<uint4*>(&clT[(blockIdx.x * 64 + qq) * 32 + 16 + half * 8]) = zv;
  }
}

// ---------- fused hat GEMM via MFMA. C=256 x Q=128 tile, split-K over p-halves.
// 2x2 wave tiles (64c x 64q) -> 1.0 KB LDS-read per mfma (was 1.5).
// Single-barrier fused chunks: {fs-DMA(k+1), v-regs(k+2), dgen(k+1)->aT[alt],
// mmain(k), syncthreads}. grid 256 (XCD-swizzled), block 512, LDS 96KB, 1 blk/CU.
__global__ __launch_bounds__(512, 2) void k_hat(
    const unsigned short* __restrict__ fs1, const unsigned short* __restrict__ fs2,
    const unsigned short* __restrict__ clT1, const unsigned short* __restrict__ clT2,
    float* __restrict__ hat1, float* __restrict__ hat2,
    float* __restrict__ pt1, float* __restrict__ pt2){
  const int t = threadIdx.x;
  const int bid = blockIdx.x;
  const int xcd = bid & 7, slot = bid >> 3;  // slot 0..31
  const int z = xcd >> 1;                    // 0..3 -> (n,i); 2 XCDs per (n,i)
  const int n = z & 1, i = z >> 1;
  const int x = slot * 2 + (xcd & 1);        // 0..63
  const int qt = x >> 1, ph = x & 1;         // 32 q-tiles(128) x 2 p-halves
  const int q0 = qt * 128;
  const int pbase = ph * 2048;

  const unsigned short* fs = (i ? fs2 : fs1) + n * C_CH * HW_SZ;
  const unsigned short* uT = (i ? clT1 : clT2) + n * 32 * HW_SZ;  // q-side [HW][32]
  const unsigned short* vT = (i ? clT2 : clT1) + n * 32 * HW_SZ;  // p-side [HW][32]
  float* out = (ph ? (i ? pt2 : pt1) : (i ? hat2 : hat1)) + n * C_CH * HW_SZ;

  __shared__ __align__(16) unsigned short fsA[2][C_CH * 64];  // 32KB each: [c][p swz]
  __shared__ __align__(16) unsigned short aT[2][128 * 64];    // 16KB each: [q][p swz]

  const int wv = t >> 6, l = t & 63;
  const int g4 = l >> 4, lr16 = l & 15;      // d-gen (16x16)
  const int g2 = l >> 5, lr32 = l & 31;      // main (32x32)

  const int pfw = wv & 3;                    // dgen p-frag
  const int qh  = wv >> 2;                   // dgen q-half (4 q-frags each)
  const int cblk = wv & 3, qblk = wv >> 2;   // mmain: c [cblk*64,+64), q [qblk*64,+64)

  // ---- one-time u fragments (k-pad zeroed at source): 4 q-frags per wave
  bf16x8 ub[4];
  #pragma unroll
  for (int j = 0; j < 4; ++j)
    ub[j] = *reinterpret_cast<const bf16x8*>(&uT[(q0 + qh * 64 + j * 16 + lr16) * 32 + g4 * 8]);

  f32x16 acc00, acc01, acc10, acc11;         // [cf][qf]
  #pragma unroll
  for (int r = 0; r < 16; ++r){ acc00[r] = 0.f; acc01[r] = 0.f; acc10[r] = 0.f; acc11[r] = 0.f; }
  const f32x4 zz = {0.f, 0.f, 0.f, 0.f};

  // ---- per-thread byte offsets (computed once)
  // fsA: LDS chunk d holds src col16 u = (d&7) ^ (c&7) ^ (((c>>3)&1)<<2), c = d>>3
  int fs_src[4];
  #pragma unroll
  for (int it = 0; it < 4; ++it){
    int d = it * 512 + t; int c = d >> 3, sl = d & 7;
    int u = sl ^ (c & 7) ^ (((c >> 3) & 1) << 2);
    fs_src[it] = c * (HW_SZ * 2) + u * 16;
  }
  // v global source (per-lane register load, bf16x8 = 16B)
  const char* vbase = (const char*)vT;
  const int vgo = (pfw * 16 + lr16) * 64 + g4 * 16;  // bytes within chunk
  // dgen aT write: q = qh*64 + j*16 + lr16; chunk slot = pfw*2+(g4>>1);
  // j walk: slot bits unchanged (q>>3 parity fixed), +2048 bytes per j
  unsigned atw0;
  {
    int qd = qh * 64 + lr16;
    int sw = (pfw * 2 + (g4 >> 1)) ^ (qd & 7) ^ (((qd >> 3) & 1) << 2);
    atw0 = qd * 128 + sw * 16 + (g4 & 1) * 8;
  }
  // mmain reads: logical chunk = ks*2 + g2 -> base offset ^ (ks<<5)
  unsigned afo[2], bqo[2];
  #pragma unroll
  for (int cf = 0; cf < 2; ++cf){
    int crow = cblk * 64 + cf * 32 + lr32;
    afo[cf] = crow * 128 + ((g2 ^ (crow & 7) ^ (((crow >> 3) & 1) << 2)) << 4);
  }
  #pragma unroll
  for (int qf = 0; qf < 2; ++qf){
    int qrow = qblk * 64 + qf * 32 + lr32;
    bqo[qf] = qrow * 128 + ((g2 ^ (qrow & 7) ^ (((qrow >> 3) & 1) << 2)) << 4);
  }

  auto vload = [&](int kk) -> uint4 {
    return *reinterpret_cast<const uint4*>(vbase + (pbase + kk * 64) * 64 + vgo);
  };
  auto stage_fs = [&](unsigned short* dstbase, int p0){
    const char* src = (const char*)fs + p0 * 2;
    #pragma unroll
    for (int it = 0; it < 4; ++it)
      gload16(src + fs_src[it], dstbase + (it * 512 + wv * 64) * 8);
  };
  auto dgen = [&](uint4 vr, char* atB){
    bf16x8 av = *reinterpret_cast<bf16x8*>(&vr);
    #pragma unroll
    for (int j = 0; j < 4; ++j){
      f32x4 d = __builtin_amdgcn_mfma_f32_16x16x32_bf16(av, ub[j], zz, 0, 0, 0);
      uint2 pk;
      pk.x = cvtpk(tanh_fast(d[0]), tanh_fast(d[1]));
      pk.y = cvtpk(tanh_fast(d[2]), tanh_fast(d[3]));
      *reinterpret_cast<uint2*>(atB + atw0 + j * 2048) = pk;
    }
  };
  auto mmain = [&](const char* faB, const char* atB){
    #pragma unroll
    for (int ks = 0; ks < 4; ++ks){
      unsigned kx = (unsigned)(ks << 5);
      bf16x8 a0 = *reinterpret_cast<const bf16x8*>(faB + (afo[0] ^ kx));
      bf16x8 a1 = *reinterpret_cast<const bf16x8*>(faB + (afo[1] ^ kx));
      bf16x8 b0 = *reinterpret_cast<const bf16x8*>(atB + (bqo[0] ^ kx));
      bf16x8 b1 = *reinterpret_cast<const bf16x8*>(atB + (bqo[1] ^ kx));
      acc00 = __builtin_amdgcn_mfma_f32_32x32x16_bf16(a0, b0, acc00, 0, 0, 0);
      acc01 = __builtin_amdgcn_mfma_f32_32x32x16_bf16(a0, b1, acc01, 0, 0, 0);
      acc10 = __builtin_amdgcn_mfma_f32_32x32x16_bf16(a1, b0, acc10, 0, 0, 0);
      acc11 = __builtin_amdgcn_mfma_f32_32x32x16_bf16(a1, b1, acc11, 0, 0, 0);
    }
  };

  // ---- prologue: v(0),v(1) in regs; fs chunk0 DMA; a(0) -> aT[0]
  uint4 va = vload(0);
  uint4 vb = vload(1);
  stage_fs(fsA[0], pbase);
  dgen(va, (char*)aT[0]);
  __syncthreads();                            // aT[0] + fsA[0] ready

  // ---- main loop: 32 chunks, one barrier per chunk, unrolled x2 (static buffers).
  // Tail overreads (fs chunk 32, v chunks 33/34; final wasted dgen) land in
  // allocated ws regions / dead buffers -- harmless by construction.
  #pragma unroll 1
  for (int k2 = 0; k2 < 16; ++k2){
    {
      const int k = 2 * k2;
      stage_fs(fsA[1], pbase + (k + 1) * 64);   // DMA next chunk (in flight through compute)
      va = vload(k + 2);                        // v for chunk k+2
      dgen(vb, (char*)aT[1]);                   // a(k+1), pure reg/MFMA/VALU
      mmain((const char*)fsA[0], (const char*)aT[0]);
      __syncthreads();
    }
    {
      const int k = 2 * k2 + 1;
      stage_fs(fsA[0], pbase + (k + 1) * 64);
      vb = vload(k + 2);
      dgen(va, (char*)aT[0]);
      mmain((const char*)fsA[1], (const char*)aT[1]);
      __syncthreads();
    }
  }

  // ---- store: 32x32 C-layout: col(=q)=lane&31, row(=c)=(reg&3)+8*(reg>>2)+4*(lane>>5)
  const int qcol = q0 + qblk * 64 + lr32;
  #pragma unroll
  for (int r = 0; r < 16; ++r){
    int cr = (r & 3) + 8 * (r >> 2) + 4 * g2;
    out[(cblk * 64 + cr) * HW_SZ + qcol] = acc00[r];
    out[(cblk * 64 + cr) * HW_SZ + qcol + 32] = acc01[r];
    out[(cblk * 64 + 32 + cr) * HW_SZ + qcol] = acc10[r];
    out[(cblk * 64 + 32 + cr) * HW_SZ + qcol + 32] = acc11[r];
  }
}

// ---------- l2norm(channels) of (part0+part1) + residual + relu (in-place into part0)
// + stage-2 conv (R8 two-pass form)
__global__ void k_norm(float* __restrict__ hat1, float* __restrict__ hat2,
                       const float* __restrict__ pt1, const float* __restrict__ pt2,
                       const float* __restrict__ f1, const float* __restrict__ f2,
                       const float* __restrict__ cw1, const float* __restrict__ cw2,
                       const float* __restrict__ cb1, const float* __restrict__ cb2,
                       float* __restrict__ cv2){
  const int i = blockIdx.z, n = blockIdx.y, t = threadIdx.x;
  const int ql = t & 63, cg = t >> 6;
  const int q = blockIdx.x * 64 + ql;
  float* hat = (i ? hat2 : hat1) + n * C_CH * HW_SZ;
  const float* pt = (i ? pt2 : pt1) + n * C_CH * HW_SZ;
  const float* f = (i ? f2 : f1) + n * C_CH * HW_SZ;
  __shared__ float ws[C_CH];
  __shared__ float red[4][72];
  __shared__ float invs[64];
  ws[t] = (i ? cw2 : cw1)[t];
  __syncthreads();
  float s = 0.f;
  #pragma unroll 8
  for (int c = cg * 64; c < cg * 64 + 64; ++c){
    float h = hat[c * HW_SZ + q] + pt[c * HW_SZ + q];
    s += h * h;
  }
  red[cg][ql] = s; __syncthreads();
  if (t < 64){
    float ss = red[0][t] + red[1][t] + red[2][t] + red[3][t];
    invs[t] = 1.0f / fmaxf(sqrtf(ss), 1e-12f);
  }
  __syncthreads();
  const float inv = invs[ql];
  float ca = 0.f;
  #pragma unroll 8
  for (int c = cg * 64; c < cg * 64 + 64; ++c){
    float h = hat[c * HW_SZ + q] + pt[c * HW_SZ + q];
    float vv = fmaxf(h * inv + f[c * HW_SZ + q], 0.0f);
    hat[c * HW_SZ + q] = vv;  // in-place: only this thread touches [c][q]
    ca += ws[c] * vv;
  }
  red[cg][ql] = ca; __syncthreads();
  if (t < 64){
    float ss = red[0][t] + red[1][t] + red[2][t] + red[3][t] + (i ? cb2[0] : cb1[0]);
    cv2[(i * 2 + n) * HW_SZ + blockIdx.x * 64 + t] = ss;
  }
}

// ---------- final: out_i = pr2_i * fp_i
__global__ void k_final(const float* __restrict__ fp1, const float* __restrict__ fp2,
                        const float* __restrict__ pr2, float* __restrict__ outp){
  const int i = blockIdx.z;
  const int idx4 = (blockIdx.x * 256 + threadIdx.x) * 4;
  const int n = idx4 >> 20;
  const int q = idx4 & (HW_SZ - 1);
  const float* fp = i ? fp2 : fp1;
  float4 vv = *reinterpret_cast<const float4*>(&fp[idx4]);
  float4 pp = *reinterpret_cast<const float4*>(&pr2[(i * 2 + n) * HW_SZ + q]);
  float4 o; o.x = vv.x * pp.x; o.y = vv.y * pp.y; o.z = vv.z * pp.z; o.w = vv.w * pp.w;
  *reinterpret_cast<float4*>(&outp[i * (C_CH * HW_SZ * N_B) + idx4]) = o;
}

extern "C" void kernel_launch(void* const* d_in, const int* in_sizes, int n_in,
                              void* d_out, int out_size, void* d_ws, size_t ws_size,
                              hipStream_t stream){
  const float* f1  = (const float*)d_in[0];
  const float* f2  = (const float*)d_in[1];
  const float* pw1 = (const float*)d_in[2];
  const float* pb1 = (const float*)d_in[3];
  const float* pw2 = (const float*)d_in[4];
  const float* pb2 = (const float*)d_in[5];
  const float* cw1 = (const float*)d_in[6];
  const float* cb1 = (const float*)d_in[7];
  const float* cw2 = (const float*)d_in[8];
  const float* cb2 = (const float*)d_in[9];
  float* ws = (float*)d_ws;
  // layout (float offsets): HAT = part0 (doubles as FP), PT = part1
  float* HAT1 = ws;                                        // 2,097,152 floats each
  float* HAT2 = ws + 2097152;
  float* PT1  = ws + 4194304;
  float* PT2  = ws + 6291456;
  unsigned short* FS1 = (unsigned short*)(ws + 8388608);   // bf16 [C][HW] per n
  unsigned short* FS2 = (unsigned short*)(ws + 9437184);
  unsigned short* CLT1 = (unsigned short*)(ws + 10485760); // bf16 [HW][32] per n
  unsigned short* CLT2 = (unsigned short*)(ws + 10616832);
  float* CV1  = ws + 10747904;
  float* PR1  = ws + 10764288;
  float* CV2  = ws + 10780672;
  float* PR2  = ws + 10797056;                             // end 10,813,440 floats ~= 43.3 MiB
  float* outp = (float*)d_out;

  k_conv1   <<<dim3(64, 2, 2), 256, 0, stream>>>(f1, f2, cw1, cw2, cb1, cb2, CV1);
  k_softmax <<<4, 256, 0, stream>>>(CV1, PR1);
  k_scale_cl<<<dim3(64, 2, 2), 256, 0, stream>>>(f1, f2, PR1, pw1, pw2, pb1, pb2,
                                                 FS1, FS2, CLT1, CLT2);
  k_hat     <<<256, 512, 0, stream>>>(FS1, FS2, CLT1, CLT2, HAT1, HAT2, PT1, PT2);
  k_norm    <<<dim3(64, 2, 2), 256, 0, stream>>>(HAT1, HAT2, PT1, PT2, f1, f2,
                                                 cw1, cw2, cb1, cb2, CV2);
  k_softmax <<<4, 256, 0, stream>>>(CV2, PR2);
  k_final   <<<dim3(2048, 1, 2), 256, 0, stream>>>(HAT1, HAT2, PR2, outp);
}

// Round 12
// 96.689 us; speedup vs baseline: 1.5829x; 1.0897x over previous
//
#include <hip/hip_runtime.h>
#include <hip/hip_bf16.h>
#include <math.h>

#define N_B 2
#define C_CH 256
#define HW_SZ 4096
#define CL_CH 16

typedef __bf16 bf16x8 __attribute__((ext_vector_type(8)));
typedef float f32x4 __attribute__((ext_vector_type(4)));
typedef float f32x16 __attribute__((ext_vector_type(16)));

__device__ __forceinline__ unsigned short f2bf(float x){
  __hip_bfloat16 b = __float2bfloat16(x);   // RTNE
  return *reinterpret_cast<unsigned short*>(&b);
}
__device__ __forceinline__ float bf2f(unsigned short u){
  unsigned int w = ((unsigned int)u) << 16;
  return *reinterpret_cast<float*>(&w);
}
// packed f32x2 -> bf16x2 (single v_cvt_pk_bf16_f32)
__device__ __forceinline__ unsigned int cvtpk(float a, float b){
  unsigned int r;
  asm("v_cvt_pk_bf16_f32 %0, %1, %2" : "=v"(r) : "v"(a), "v"(b));
  return r;
}
// tanh = 1 - 2*rcp(1+e^{2x}); NaN-safe at +-inf; rcp err ~1e-7 (<< bf16 ulp)
__device__ __forceinline__ float tanh_fast(float x){
  float e = __expf(2.0f * x);
  return fmaf(-2.0f, __builtin_amdgcn_rcpf(1.0f + e), 1.0f);
}
// async global->LDS, 16B per lane; dst must be wave-uniform base (+lane*16 implicit)
__device__ __forceinline__ void gload16(const void* gsrc, void* lds_dst){
  __builtin_amdgcn_global_load_lds(
      (const __attribute__((address_space(1))) unsigned int*)gsrc,
      (__attribute__((address_space(3))) unsigned int*)lds_dst, 16, 0, 0);
}

// ---------- Stage-1 conv (C->1)
__global__ void k_conv1(const float* __restrict__ f1, const float* __restrict__ f2,
                        const float* __restrict__ w1, const float* __restrict__ w2,
                        const float* __restrict__ b1, const float* __restrict__ b2,
                        float* __restrict__ cv){
  const int i = blockIdx.z, n = blockIdx.y, t = threadIdx.x;
  const int ql = t & 63, cg = t >> 6;
  const int q = blockIdx.x * 64 + ql;
  const float* f = (i ? f2 : f1) + n * C_CH * HW_SZ;
  const float* w = i ? w2 : w1;
  __shared__ float ws[C_CH];
  __shared__ float red[4][72];
  ws[t] = w[t];
  __syncthreads();
  float acc = 0.f;
  #pragma unroll 8
  for (int c = cg * 64; c < cg * 64 + 64; ++c)
    acc += f[c * HW_SZ + q] * ws[c];
  red[cg][ql] = acc;
  __syncthreads();
  if (t < 64){
    float s = red[0][t] + red[1][t] + red[2][t] + red[3][t] + (i ? b2[0] : b1[0]);
    cv[(i * 2 + n) * HW_SZ + blockIdx.x * 64 + t] = s;
  }
}

// ---------- fs_i = bf16(pr_i * f_i) ; clT_i[q][0..15] = bf16(pw_i @ (pr*f) + pb_i)
// pr computed INLINE from cv (softmax folded in; kills the k_softmax launch).
__global__ void k_scale_cl(const float* __restrict__ f1, const float* __restrict__ f2,
                           const float* __restrict__ cv,
                           const float* __restrict__ pw1, const float* __restrict__ pw2,
                           const float* __restrict__ pb1, const float* __restrict__ pb2,
                           unsigned short* __restrict__ fs1, unsigned short* __restrict__ fs2,
                           unsigned short* __restrict__ clT1, unsigned short* __restrict__ clT2){
  const int i = blockIdx.z, n = blockIdx.y, t = threadIdx.x;
  const int ql = t & 63, cg = t >> 6;
  const int q = blockIdx.x * 64 + ql;
  const float* f = (i ? f2 : f1) + n * C_CH * HW_SZ;
  unsigned short* fs = (i ? fs2 : fs1) + n * C_CH * HW_SZ;
  unsigned short* clT = (i ? clT2 : clT1) + n * 32 * HW_SZ;
  const float* pw = i ? pw2 : pw1;
  const float* pb = i ? pb2 : pb1;
  const float* cvrow = cv + (i * 2 + n) * HW_SZ;
  __shared__ float wls[CL_CH * C_CH];
  __shared__ float red[4][CL_CH][66];
  __shared__ float smr[256];
  #pragma unroll
  for (int j = 0; j < 16; j++) wls[j * 256 + t] = pw[j * 256 + t];
  // inline softmax over the 4096-row
  float sv[16];
  float m = -1e30f;
  #pragma unroll
  for (int j = 0; j < 16; j++){ sv[j] = cvrow[j * 256 + t]; m = fmaxf(m, sv[j]); }
  smr[t] = m; __syncthreads();
  for (int s = 128; s > 0; s >>= 1){ if (t < s) smr[t] = fmaxf(smr[t], smr[t + s]); __syncthreads(); }
  m = smr[0]; __syncthreads();
  float sum = 0.f;
  #pragma unroll
  for (int j = 0; j < 16; j++) sum += __expf(sv[j] - m);
  smr[t] = sum; __syncthreads();
  for (int s = 128; s > 0; s >>= 1){ if (t < s) smr[t] += smr[t + s]; __syncthreads(); }
  const float p = __expf(cvrow[q] - m) * (1.0f / smr[0]);

  float acc[16];
  #pragma unroll
  for (int k = 0; k < 16; k++) acc[k] = 0.f;
  for (int c = cg * 64; c < cg * 64 + 64; ++c){
    float vv = f[c * HW_SZ + q] * p;
    fs[c * HW_SZ + q] = f2bf(vv);
    #pragma unroll
    for (int k = 0; k < 16; k++) acc[k] += wls[k * 256 + c] * vv;
  }
  #pragma unroll
  for (int k = 0; k < 16; k++) red[cg][k][ql] = acc[k];
  __syncthreads();
  #pragma unroll
  for (int j = 0; j < 4; j++){
    int e = j * 256 + t; int k = e >> 6, qq = e & 63;
    float s = red[0][k][qq] + red[1][k][qq] + red[2][k][qq] + red[3][k][qq] + pb[k];
    clT[(blockIdx.x * 64 + qq) * 32 + k] = f2bf(s);
  }
  // zero the k in [16,32) pad
  if (t < 128){
    uint4 zv = {0u, 0u, 0u, 0u};
    int qq = t >> 1, half = t & 1;
    *reinterpret_cast<uint4*>(&clT[(blockIdx.x * 64 + qq) * 32 + 16 + half * 8]) = zv;
  }
}

// ---------- fused hat GEMM via MFMA. C=256 x Q=128 tile, split-K over p-halves.
// R11 geometry + COUNTED-VMCNT schedule (T3/T4): two drain-free barriers per
// chunk; DMA(k+1) stays in flight across barriers; dgen's register-v wait
// (vload issued AFTER DMA in prior body; vmcnt retires in order) guarantees
// DMA(k) done per-wave before barrier#1 -> mmain(k) safe.
__global__ __launch_bounds__(512, 2) void k_hat(
    const unsigned short* __restrict__ fs1, const unsigned short* __restrict__ fs2,
    const unsigned short* __restrict__ clT1, const unsigned short* __restrict__ clT2,
    float* __restrict__ hat1, float* __restrict__ hat2,
    float* __restrict__ pt1, float* __restrict__ pt2){
  const int t = threadIdx.x;
  const int bid = blockIdx.x;
  const int xcd = bid & 7, slot = bid >> 3;  // slot 0..31
  const int z = xcd >> 1;                    // 0..3 -> (n,i); 2 XCDs per (n,i)
  const int n = z & 1, i = z >> 1;
  const int x = slot * 2 + (xcd & 1);        // 0..63
  const int qt = x >> 1, ph = x & 1;         // 32 q-tiles(128) x 2 p-halves
  const int q0 = qt * 128;
  const int pbase = ph * 2048;

  const unsigned short* fs = (i ? fs2 : fs1) + n * C_CH * HW_SZ;
  const unsigned short* uT = (i ? clT1 : clT2) + n * 32 * HW_SZ;  // q-side [HW][32]
  const unsigned short* vT = (i ? clT2 : clT1) + n * 32 * HW_SZ;  // p-side [HW][32]
  float* out = (ph ? (i ? pt2 : pt1) : (i ? hat2 : hat1)) + n * C_CH * HW_SZ;

  __shared__ __align__(16) unsigned short fsA[2][C_CH * 64];  // 32KB each: [c][p swz]
  __shared__ __align__(16) unsigned short aT[2][128 * 64];    // 16KB each: [q][p swz]

  const int wv = t >> 6, l = t & 63;
  const int g4 = l >> 4, lr16 = l & 15;      // d-gen (16x16)
  const int g2 = l >> 5, lr32 = l & 31;      // main (32x32)

  const int pfw = wv & 3;                    // dgen p-frag
  const int qh  = wv >> 2;                   // dgen q-half (4 q-frags each)
  const int cblk = wv & 3, qblk = wv >> 2;   // mmain: c [cblk*64,+64), q [qblk*64,+64)

  // ---- one-time u fragments (k-pad zeroed at source): 4 q-frags per wave
  bf16x8 ub[4];
  #pragma unroll
  for (int j = 0; j < 4; ++j)
    ub[j] = *reinterpret_cast<const bf16x8*>(&uT[(q0 + qh * 64 + j * 16 + lr16) * 32 + g4 * 8]);

  f32x16 acc00, acc01, acc10, acc11;         // [cf][qf]
  #pragma unroll
  for (int r = 0; r < 16; ++r){ acc00[r] = 0.f; acc01[r] = 0.f; acc10[r] = 0.f; acc11[r] = 0.f; }
  const f32x4 zz = {0.f, 0.f, 0.f, 0.f};

  // ---- per-thread byte offsets (computed once)
  int fs_src[4];
  #pragma unroll
  for (int it = 0; it < 4; ++it){
    int d = it * 512 + t; int c = d >> 3, sl = d & 7;
    int u = sl ^ (c & 7) ^ (((c >> 3) & 1) << 2);
    fs_src[it] = c * (HW_SZ * 2) + u * 16;
  }
  const int vgo = (pfw * 16 + lr16) * 64 + g4 * 16;  // per-lane byte off within v chunk
  unsigned atw0;
  {
    int qd = qh * 64 + lr16;
    int sw = (pfw * 2 + (g4 >> 1)) ^ (qd & 7) ^ (((qd >> 3) & 1) << 2);
    atw0 = qd * 128 + sw * 16 + (g4 & 1) * 8;
  }
  unsigned afo[2], bqo[2];
  #pragma unroll
  for (int cf = 0; cf < 2; ++cf){
    int crow = cblk * 64 + cf * 32 + lr32;
    afo[cf] = crow * 128 + ((g2 ^ (crow & 7) ^ (((crow >> 3) & 1) << 2)) << 4);
  }
  #pragma unroll
  for (int qf = 0; qf < 2; ++qf){
    int qrow = qblk * 64 + qf * 32 + lr32;
    bqo[qf] = qrow * 128 + ((g2 ^ (qrow & 7) ^ (((qrow >> 3) & 1) << 2)) << 4);
  }

  auto stage_fs = [&](unsigned short* dstbase, const char* src){
    #pragma unroll
    for (int it = 0; it < 4; ++it)
      gload16(src + fs_src[it], dstbase + (it * 512 + wv * 64) * 8);
  };
  auto dgen = [&](uint4 vr, char* atB){
    bf16x8 av = *reinterpret_cast<bf16x8*>(&vr);
    #pragma unroll
    for (int j = 0; j < 4; ++j){
      f32x4 d = __builtin_amdgcn_mfma_f32_16x16x32_bf16(av, ub[j], zz, 0, 0, 0);
      uint2 pk;
      pk.x = cvtpk(tanh_fast(d[0]), tanh_fast(d[1]));
      pk.y = cvtpk(tanh_fast(d[2]), tanh_fast(d[3]));
      *reinterpret_cast<uint2*>(atB + atw0 + j * 2048) = pk;
    }
  };
  auto mmain = [&](const char* faB, const char* atB){
    #pragma unroll
    for (int ks = 0; ks < 4; ++ks){
      unsigned kx = (unsigned)(ks << 5);
      bf16x8 a0 = *reinterpret_cast<const bf16x8*>(faB + (afo[0] ^ kx));
      bf16x8 a1 = *reinterpret_cast<const bf16x8*>(faB + (afo[1] ^ kx));
      bf16x8 b0 = *reinterpret_cast<const bf16x8*>(atB + (bqo[0] ^ kx));
      bf16x8 b1 = *reinterpret_cast<const bf16x8*>(atB + (bqo[1] ^ kx));
      acc00 = __builtin_amdgcn_mfma_f32_32x32x16_bf16(a0, b0, acc00, 0, 0, 0);
      acc01 = __builtin_amdgcn_mfma_f32_32x32x16_bf16(a0, b1, acc01, 0, 0, 0);
      acc10 = __builtin_amdgcn_mfma_f32_32x32x16_bf16(a1, b0, acc10, 0, 0, 0);
      acc11 = __builtin_amdgcn_mfma_f32_32x32x16_bf16(a1, b1, acc11, 0, 0, 0);
    }
  };

  // advancing pointers (hot loop: one add each)
  const char* fpp = (const char*)fs + pbase * 2;       // fs chunk base, +128B/chunk
  const char* vp  = (const char*)vT + pbase * 64 + vgo;// per-lane v ptr, +4096B/chunk

  // ---- prologue: DMA chunk0 FIRST, then vloads (so vload retirement implies DMA done)
  stage_fs(fsA[0], fpp); fpp += 128;
  uint4 va = *reinterpret_cast<const uint4*>(vp);          // v chunk 0
  uint4 vb = *reinterpret_cast<const uint4*>(vp + 4096);   // v chunk 1
  vp += 8192;
  dgen(va, (char*)aT[0]);   // waits va (counted vmcnt) => chunk-0 DMA retired per-wave

  // ---- main loop: 32 chunks, 2 drain-free barriers each, unrolled x2.
  // Tail overreads (fs chunk 32, v chunk 33; wasted dgen) land in allocated ws.
  #pragma unroll 1
  for (int k2 = 0; k2 < 16; ++k2){
    { // k = 2*k2 (even): cur = fsA[0]/aT[0]
      stage_fs(fsA[1], fpp); fpp += 128;                 // DMA chunk k+1
      va = *reinterpret_cast<const uint4*>(vp); vp += 4096;  // v chunk k+2
      dgen(vb, (char*)aT[1]);                            // a(k+1); waits v(k+1) => DMA(k) done
      asm volatile("s_waitcnt lgkmcnt(0)" ::: "memory");
      __builtin_amdgcn_sched_barrier(0);
      __builtin_amdgcn_s_barrier();                      // barrier #1 (no vmcnt drain)
      __builtin_amdgcn_sched_barrier(0);
      mmain((const char*)fsA[0], (const char*)aT[0]);
      __builtin_amdgcn_sched_barrier(0);
      __builtin_amdgcn_s_barrier();                      // barrier #2 (WAR protection)
      __builtin_amdgcn_sched_barrier(0);
    }
    { // k odd: cur = fsA[1]/aT[1]
      stage_fs(fsA[0], fpp); fpp += 128;
      vb = *reinterpret_cast<const uint4*>(vp); vp += 4096;
      dgen(va, (char*)aT[0]);
      asm volatile("s_waitcnt lgkmcnt(0)" ::: "memory");
      __builtin_amdgcn_sched_barrier(0);
      __builtin_amdgcn_s_barrier();
      __builtin_amdgcn_sched_barrier(0);
      mmain((const char*)fsA[1], (const char*)aT[1]);
      __builtin_amdgcn_sched_barrier(0);
      __builtin_amdgcn_s_barrier();
      __builtin_amdgcn_sched_barrier(0);
    }
  }

  // ---- store: 32x32 C-layout: col(=q)=lane&31, row(=c)=(reg&3)+8*(reg>>2)+4*(lane>>5)
  const int qcol = q0 + qblk * 64 + lr32;
  #pragma unroll
  for (int r = 0; r < 16; ++r){
    int cr = (r & 3) + 8 * (r >> 2) + 4 * g2;
    out[(cblk * 64 + cr) * HW_SZ + qcol] = acc00[r];
    out[(cblk * 64 + cr) * HW_SZ + qcol + 32] = acc01[r];
    out[(cblk * 64 + 32 + cr) * HW_SZ + qcol] = acc10[r];
    out[(cblk * 64 + 32 + cr) * HW_SZ + qcol + 32] = acc11[r];
  }
}

// ---------- l2norm(channels) of (part0+part1) + residual + relu (in-place into part0)
// + stage-2 conv. h = hat+pt cached in LDS as bf16 (single global read of hat/pt).
__global__ void k_norm(float* __restrict__ hat1, float* __restrict__ hat2,
                       const float* __restrict__ pt1, const float* __restrict__ pt2,
                       const float* __restrict__ f1, const float* __restrict__ f2,
                       const float* __restrict__ cw1, const float* __restrict__ cw2,
                       const float* __restrict__ cb1, const float* __restrict__ cb2,
                       float* __restrict__ cv2){
  const int i = blockIdx.z, n = blockIdx.y, t = threadIdx.x;
  const int ql = t & 63, cg = t >> 6;
  const int q = blockIdx.x * 64 + ql;
  float* hat = (i ? hat2 : hat1) + n * C_CH * HW_SZ;
  const float* pt = (i ? pt2 : pt1) + n * C_CH * HW_SZ;
  const float* f = (i ? f2 : f1) + n * C_CH * HW_SZ;
  __shared__ float ws[C_CH];
  __shared__ float red[4][72];
  __shared__ float invs[64];
  __shared__ unsigned short hLs[C_CH][66];   // bf16 h cache, pad 66
  ws[t] = (i ? cw2 : cw1)[t];
  __syncthreads();
  float s = 0.f;
  #pragma unroll 8
  for (int c = cg * 64; c < cg * 64 + 64; ++c){
    float h = hat[c * HW_SZ + q] + pt[c * HW_SZ + q];
    hLs[c][ql] = f2bf(h);
    s += h * h;
  }
  red[cg][ql] = s; __syncthreads();
  if (t < 64){
    float ss = red[0][t] + red[1][t] + red[2][t] + red[3][t];
    invs[t] = 1.0f / fmaxf(sqrtf(ss), 1e-12f);
  }
  __syncthreads();
  const float inv = invs[ql];
  float ca = 0.f;
  #pragma unroll 8
  for (int c = cg * 64; c < cg * 64 + 64; ++c){
    float vv = fmaxf(bf2f(hLs[c][ql]) * inv + f[c * HW_SZ + q], 0.0f);
    hat[c * HW_SZ + q] = vv;  // in-place fp32: only this thread touches [c][q]
    ca += ws[c] * vv;
  }
  red[cg][ql] = ca; __syncthreads();
  if (t < 64){
    float ss = red[0][t] + red[1][t] + red[2][t] + red[3][t] + (i ? cb2[0] : cb1[0]);
    cv2[(i * 2 + n) * HW_SZ + blockIdx.x * 64 + t] = ss;
  }
}

// ---------- final: out_i = softmax(cv2)_i * fp_i (softmax folded in)
__global__ void k_final(const float* __restrict__ fp1, const float* __restrict__ fp2,
                        const float* __restrict__ cv2, float* __restrict__ outp){
  const int i = blockIdx.z, t = threadIdx.x;
  const int idx4 = (blockIdx.x * 256 + t) * 4;
  const int n = idx4 >> 20;
  const int q = idx4 & (HW_SZ - 1);
  const float* cvrow = cv2 + (i * 2 + n) * HW_SZ;
  __shared__ float red[256];
  float sv[16];
  float m = -1e30f;
  #pragma unroll
  for (int j = 0; j < 16; j++){ sv[j] = cvrow[j * 256 + t]; m = fmaxf(m, sv[j]); }
  red[t] = m; __syncthreads();
  for (int s = 128; s > 0; s >>= 1){ if (t < s) red[t] = fmaxf(red[t], red[t + s]); __syncthreads(); }
  m = red[0]; __syncthreads();
  float sum = 0.f;
  #pragma unroll
  for (int j = 0; j < 16; j++) sum += __expf(sv[j] - m);
  red[t] = sum; __syncthreads();
  for (int s = 128; s > 0; s >>= 1){ if (t < s) red[t] += red[t + s]; __syncthreads(); }
  const float invS = 1.0f / red[0];

  const float* fp = i ? fp2 : fp1;
  float4 vv = *reinterpret_cast<const float4*>(&fp[idx4]);
  float4 o;
  o.x = vv.x * (__expf(cvrow[q + 0] - m) * invS);
  o.y = vv.y * (__expf(cvrow[q + 1] - m) * invS);
  o.z = vv.z * (__expf(cvrow[q + 2] - m) * invS);
  o.w = vv.w * (__expf(cvrow[q + 3] - m) * invS);
  *reinterpret_cast<float4*>(&outp[i * (C_CH * HW_SZ * N_B) + idx4]) = o;
}

extern "C" void kernel_launch(void* const* d_in, const int* in_sizes, int n_in,
                              void* d_out, int out_size, void* d_ws, size_t ws_size,
                              hipStream_t stream){
  const float* f1  = (const float*)d_in[0];
  const float* f2  = (const float*)d_in[1];
  const float* pw1 = (const float*)d_in[2];
  const float* pb1 = (const float*)d_in[3];
  const float* pw2 = (const float*)d_in[4];
  const float* pb2 = (const float*)d_in[5];
  const float* cw1 = (const float*)d_in[6];
  const float* cb1 = (const float*)d_in[7];
  const float* cw2 = (const float*)d_in[8];
  const float* cb2 = (const float*)d_in[9];
  float* ws = (float*)d_ws;
  // layout (float offsets): HAT = part0 (doubles as FP), PT = part1
  float* HAT1 = ws;                                        // 2,097,152 floats each
  float* HAT2 = ws + 2097152;
  float* PT1  = ws + 4194304;
  float* PT2  = ws + 6291456;
  unsigned short* FS1 = (unsigned short*)(ws + 8388608);   // bf16 [C][HW] per n
  unsigned short* FS2 = (unsigned short*)(ws + 9437184);
  unsigned short* CLT1 = (unsigned short*)(ws + 10485760); // bf16 [HW][32] per n
  unsigned short* CLT2 = (unsigned short*)(ws + 10616832);
  float* CV1  = ws + 10747904;
  float* CV2  = ws + 10764288;                             // end 10,780,672 floats ~= 43.1 MiB
  float* outp = (float*)d_out;

  k_conv1   <<<dim3(64, 2, 2), 256, 0, stream>>>(f1, f2, cw1, cw2, cb1, cb2, CV1);
  k_scale_cl<<<dim3(64, 2, 2), 256, 0, stream>>>(f1, f2, CV1, pw1, pw2, pb1, pb2,
                                                 FS1, FS2, CLT1, CLT2);
  k_hat     <<<256, 512, 0, stream>>>(FS1, FS2, CLT1, CLT2, HAT1, HAT2, PT1, PT2);
  k_norm    <<<dim3(64, 2, 2), 256, 0, stream>>>(HAT1, HAT2, PT1, PT2, f1, f2,
                                                 cw1, cw2, cb1, cb2, CV2);
  k_final   <<<dim3(2048, 1, 2), 256, 0, stream>>>(HAT1, HAT2, CV2, outp);
}